// Round 1
// baseline (1319.851 us; speedup 1.0000x reference)
//
#include <hip/hip_runtime.h>

// Shapes are fixed by the reference setup_inputs():
//   x: (8, 128, 512, 512) fp32, W: (1,128,1,1), b: (1,), out: (8,1,512,512)
static constexpr int       C_    = 128;
static constexpr long long HW_   = 512LL * 512LL;   // 262144 pixels per plane
static constexpr long long HW4_  = HW_ / 4;         // 65536 float4 per plane
static constexpr int       LOG_HW4 = 16;            // log2(HW4_)
static constexpr float     QMAX  = 127.0f;          // 2^(8-1)-1

// --- Kernel 1: quant-dequant the 128 weights into d_ws -----------------------
// scale = max|W|/127; Wq = clip(rint(W/scale), -127, 127) * scale
// rintf = round-half-to-even, matching jnp.round.
__global__ void quant_w_kernel(const float* __restrict__ W,
                               float* __restrict__ Wq) {
    __shared__ float red[C_];
    int i = threadIdx.x;
    float v = W[i];
    red[i] = fabsf(v);
    __syncthreads();
    #pragma unroll
    for (int s = C_ / 2; s > 0; s >>= 1) {
        if (i < s) red[i] = fmaxf(red[i], red[i + s]);
        __syncthreads();
    }
    float scale = red[0] / QMAX;
    float q = rintf(v / scale);
    q = fminf(fmaxf(q, -QMAX), QMAX);
    Wq[i] = q * scale;
}

// --- Kernel 2: streaming channel reduction ----------------------------------
// One thread per output float4. Per channel the wave reads 64 lanes x 16 B
// = 1 KiB contiguous (coalesced); channel stride is 1 MiB. Weights broadcast
// from LDS. Unroll gives 16 independent loads in flight per thread.
__global__ __launch_bounds__(256) void conv1x1_kernel(
    const float4* __restrict__ x, const float* __restrict__ Wq,
    const float* __restrict__ bias, float4* __restrict__ out) {
    __shared__ float w[C_];
    if (threadIdx.x < C_) w[threadIdx.x] = Wq[threadIdx.x];
    __syncthreads();

    long long tid = (long long)blockIdx.x * blockDim.x + threadIdx.x;
    long long b   = tid >> LOG_HW4;        // batch index
    long long p4  = tid & (HW4_ - 1);      // float4 index within plane
    const float4* xp = x + (b * C_) * HW4_ + p4;

    float4 acc0 = {0.f, 0.f, 0.f, 0.f};
    float4 acc1 = {0.f, 0.f, 0.f, 0.f};
    #pragma unroll 8
    for (int c = 0; c < C_; c += 2) {
        float4 v0 = xp[(long long)c * HW4_];
        float4 v1 = xp[(long long)(c + 1) * HW4_];
        float w0 = w[c], w1 = w[c + 1];
        acc0.x += v0.x * w0; acc0.y += v0.y * w0;
        acc0.z += v0.z * w0; acc0.w += v0.w * w0;
        acc1.x += v1.x * w1; acc1.y += v1.y * w1;
        acc1.z += v1.z * w1; acc1.w += v1.w * w1;
    }
    float bb = bias[0];
    float4 r;
    r.x = acc0.x + acc1.x + bb;
    r.y = acc0.y + acc1.y + bb;
    r.z = acc0.z + acc1.z + bb;
    r.w = acc0.w + acc1.w + bb;
    out[tid] = r;
}

extern "C" void kernel_launch(void* const* d_in, const int* in_sizes, int n_in,
                              void* d_out, int out_size, void* d_ws, size_t ws_size,
                              hipStream_t stream) {
    const float* x    = (const float*)d_in[0];
    const float* W    = (const float*)d_in[1];
    const float* bias = (const float*)d_in[2];
    float* out = (float*)d_out;
    float* Wq  = (float*)d_ws;   // 128 floats of scratch (re-poisoned every call,
                                 // so quant_w_kernel must run every call — it does)

    quant_w_kernel<<<1, C_, 0, stream>>>(W, Wq);

    long long n4   = (long long)out_size / 4;   // 524288 float4 outputs
    int       blk  = 256;
    int       grid = (int)((n4 + blk - 1) / blk);  // 2048 blocks
    conv1x1_kernel<<<grid, blk, 0, stream>>>((const float4*)x, Wq, bias,
                                             (float4*)out);
}